// Round 2
// baseline (1151.601 us; speedup 1.0000x reference)
//
#include <hip/hip_runtime.h>

// Problem constants (from reference setup_inputs):
//   T = 8192 tokens, H = 4096 hidden, E = 64 experts, K = 2 top-k, D = 8 devices
// Output: [D, T, H] float32 -- out[d,t,:] = mask(d,t) ? input[t,:] : 0
// mask(d,t) = any_k( expert_mapping[expert_indices[t,k]] == d )

#define T_TOK 8192
#define H_DIM 4096
#define NUM_DEV 8

// Native clang vector type: __builtin_nontemporal_store requires a vector of
// scalars, not HIP's float4 class.
typedef float vfloat4 __attribute__((ext_vector_type(4)));

// One block per (d, t) output row. 256 threads x 4 float4 = 4096 floats = row.
// blockIdx.x = d * T + t (flat row index into out) -> output offset is
// blockIdx.x * H. T is a power of two -> shift/mask to decompose.
__global__ __launch_bounds__(256)
void a2a_dispatch_kernel(const float* __restrict__ input,
                         const int* __restrict__ expert_indices,
                         const int* __restrict__ expert_mapping,
                         float* __restrict__ out)
{
    const unsigned bid = blockIdx.x;            // in [0, D*T)
    const unsigned d   = bid >> 13;             // bid / T
    const unsigned t   = bid & (T_TOK - 1);     // bid % T

    // Wave-uniform (blockIdx-derived addresses) -> scalar loads; index data is
    // tiny (64 KiB + 256 B) and stays cache-resident.
    const int e0   = expert_indices[2u * t];
    const int e1   = expert_indices[2u * t + 1];
    const int dev0 = expert_mapping[e0];
    const int dev1 = expert_mapping[e1];
    const bool hit = (dev0 == (int)d) || (dev1 == (int)d);

    const vfloat4* __restrict__ in_row =
        (const vfloat4*)(input + (size_t)t * H_DIM);
    vfloat4* __restrict__ out_row =
        (vfloat4*)(out + (size_t)bid * H_DIM);

    if (hit) {
        // Cached loads (input reused across devices; 128 MiB fits in L3);
        // nontemporal stores so the 1 GiB streaming output doesn't evict it.
#pragma unroll
        for (int k = 0; k < 4; ++k) {
            vfloat4 v = in_row[threadIdx.x + k * 256];
            __builtin_nontemporal_store(v, &out_row[threadIdx.x + k * 256]);
        }
    } else {
        const vfloat4 z = (vfloat4)(0.f);
#pragma unroll
        for (int k = 0; k < 4; ++k) {
            __builtin_nontemporal_store(z, &out_row[threadIdx.x + k * 256]);
        }
    }
}

extern "C" void kernel_launch(void* const* d_in, const int* in_sizes, int n_in,
                              void* d_out, int out_size, void* d_ws, size_t ws_size,
                              hipStream_t stream) {
    const float* input          = (const float*)d_in[0];   // [T, H] fp32
    const int*   expert_indices = (const int*)d_in[1];     // [T, K] int32
    const int*   expert_mapping = (const int*)d_in[2];     // [E]    int32
    float*       out            = (float*)d_out;           // [D, T, H] fp32

    const int grid = NUM_DEV * T_TOK;  // 65536 blocks, one 16 KiB row each
    a2a_dispatch_kernel<<<grid, 256, 0, stream>>>(input, expert_indices,
                                                  expert_mapping, out);
}